// Round 1
// baseline (415.472 us; speedup 1.0000x reference)
//
#include <hip/hip_runtime.h>
#include <stdint.h>

#define B_ 8
#define C_ 256
#define HW_ 16384
#define N_ 4
#define EPS_BN 1e-5f

typedef __bf16 bf16_t;
typedef bf16_t bf16x8 __attribute__((ext_vector_type(8)));
typedef float f32x4 __attribute__((ext_vector_type(4)));

// ---------------- 128-bit row helpers for morphology ----------------
struct B128 { uint64_t lo, hi; };
__device__ __forceinline__ B128 shr_f1(B128 x, int d) {   // >>d, fill 1
  B128 r; r.lo = (x.lo >> d) | (x.hi << (64 - d));
  r.hi = (x.hi >> d) | (~0ull << (64 - d)); return r;
}
__device__ __forceinline__ B128 shl_f1(B128 x, int d) {   // <<d, fill 1
  B128 r; r.hi = (x.hi << d) | (x.lo >> (64 - d));
  r.lo = (x.lo << d) | ((1ull << d) - 1ull); return r;
}
__device__ __forceinline__ B128 shr_f0(B128 x, int d) {
  B128 r; r.lo = (x.lo >> d) | (x.hi << (64 - d));
  r.hi = x.hi >> d; return r;
}
__device__ __forceinline__ B128 shl_f0(B128 x, int d) {
  B128 r; r.hi = (x.hi << d) | (x.lo >> (64 - d));
  r.lo = x.lo << d; return r;
}

// masks: z = (m > 0.3); erode window dp,dq in [-8,4]; dilate in [-4,8]
// byte per pixel: bits 0-3 = er_n, bits 4-7 = dl_n  (atomicOr across 4 classes)
__global__ __launch_bounds__(256) void k_masks(const float* __restrict__ m,
                                               uint32_t* __restrict__ maskw) {
  const int n = blockIdx.x, b = blockIdx.y;
  const int t = threadIdx.x, w = t >> 6, l = t & 63;
  __shared__ uint64_t zb[128][2];
  __shared__ uint64_t rE[128][2];
  __shared__ uint64_t rD[128][2];
  const float* mp = m + (size_t)(b * N_ + n) * HW_;
  for (int h = w; h < 256; h += 4) {           // one 64-px half-row per wave-iter
    uint64_t bal = __ballot(mp[h * 64 + l] > 0.3f);
    if (l == 0) zb[h >> 1][h & 1] = bal;
  }
  __syncthreads();
  if (t < 128) {                               // row pass
    B128 z; z.lo = zb[t][0]; z.hi = zb[t][1];
    B128 e = z, o = z;
    #pragma unroll
    for (int d = 1; d <= 4; ++d) { B128 s = shr_f1(z, d); e.lo &= s.lo; e.hi &= s.hi; }
    #pragma unroll
    for (int d = 1; d <= 8; ++d) { B128 s = shl_f1(z, d); e.lo &= s.lo; e.hi &= s.hi; }
    #pragma unroll
    for (int d = 1; d <= 8; ++d) { B128 s = shr_f0(z, d); o.lo |= s.lo; o.hi |= s.hi; }
    #pragma unroll
    for (int d = 1; d <= 4; ++d) { B128 s = shl_f0(z, d); o.lo |= s.lo; o.hi |= s.hi; }
    rE[t][0] = e.lo; rE[t][1] = e.hi;
    rD[t][0] = o.lo; rD[t][1] = o.hi;
  }
  __syncthreads();
  if (t < 128) {                               // column pass + emit
    const int p = t;
    B128 e; e.lo = ~0ull; e.hi = ~0ull;
    B128 o; o.lo = 0; o.hi = 0;
    for (int dp = -8; dp <= 4; ++dp) {
      int r = p + dp;
      if (r >= 0 && r < 128) { e.lo &= rE[r][0]; e.hi &= rE[r][1]; }
    }
    for (int dp = -4; dp <= 8; ++dp) {
      int r = p + dp;
      if (r >= 0 && r < 128) { o.lo |= rD[r][0]; o.hi |= rD[r][1]; }
    }
    uint32_t* base = maskw + ((size_t)b * HW_ + p * 128) / 4;
    for (int g = 0; g < 32; ++g) {
      uint32_t word = 0;
      #pragma unroll
      for (int d2 = 0; d2 < 4; ++d2) {
        int q = g * 4 + d2;
        uint32_t eb = (uint32_t)((q < 64 ? (e.lo >> q) : (e.hi >> (q - 64))) & 1ull);
        uint32_t ob = (uint32_t)((q < 64 ? (o.lo >> q) : (o.hi >> (q - 64))) & 1ull);
        word |= ((eb << n) | (ob << (4 + n))) << (8 * d2);
      }
      atomicOr(&base[g], word);
    }
  }
}

// masked sums: Smid[b][k][c], k: 0-3 er_n, 4-7 dl_n, 8 total
__global__ __launch_bounds__(256) void k_midsum(const float* __restrict__ f,
                                                const uint8_t* __restrict__ maskb,
                                                float* __restrict__ Smid) {
  const int cg = blockIdx.x;   // 16 groups of 16 channels
  const int ps = blockIdx.y;   // 4 pixel slices of 4096
  const int b  = blockIdx.z;
  const int t = threadIdx.x, w = t >> 6, l = t & 63;
  __shared__ uint8_t mloc[4096];
  {
    const uint32_t* mg = (const uint32_t*)(maskb + (size_t)b * HW_ + ps * 4096);
    uint32_t* ml = (uint32_t*)mloc;
    for (int i = t; i < 1024; i += 256) ml[i] = mg[i];
  }
  __syncthreads();
  for (int j = 0; j < 4; ++j) {
    const int c = cg * 16 + w * 4 + j;
    const float* fp = f + (size_t)(b * C_ + c) * HW_ + ps * 4096;
    float acc[9];
    #pragma unroll
    for (int k = 0; k < 9; ++k) acc[k] = 0.0f;
    for (int it = 0; it < 16; ++it) {
      const int pl = it * 256 + l * 4;
      const float4 v = *(const float4*)(fp + pl);
      const uint32_t mm = *(const uint32_t*)&mloc[pl];
      const float* vv = (const float*)&v;
      #pragma unroll
      for (int d = 0; d < 4; ++d) {
        const float x = vv[d];
        const uint32_t mk = (mm >> (8 * d)) & 0xffu;
        acc[8] += x;
        #pragma unroll
        for (int n = 0; n < 4; ++n) {
          acc[n]     += ((mk >> n) & 1u)       ? x : 0.0f;
          acc[4 + n] += ((mk >> (4 + n)) & 1u) ? x : 0.0f;
        }
      }
    }
    #pragma unroll
    for (int s = 1; s < 64; s <<= 1) {
      #pragma unroll
      for (int k = 0; k < 9; ++k) acc[k] += __shfl_xor(acc[k], s);
    }
    if (l == 0) {
      #pragma unroll
      for (int k = 0; k < 9; ++k)
        atomicAdd(&Smid[(size_t)(b * 9 + k) * C_ + c], acc[k]);
    }
  }
}

// G[b] = mid12^T-products; const[b,c] = sum_k mid[k,c]*w[k], w[k]=sum_c mid[k,c]*t_f[c]
__global__ __launch_bounds__(256) void k_G(const float* __restrict__ Smid,
    const float* __restrict__ gf, const float* __restrict__ bfp,
    const float* __restrict__ muf, const float* __restrict__ vf,
    float* __restrict__ G, float* __restrict__ constb) {
  const int x = blockIdx.x;  // 4 row-slabs of 64
  const int b = blockIdx.y;
  const int t = threadIdx.x;
  __shared__ float mid[12][257];
  __shared__ float wk[12];
  {
    const float* S = Smid + (size_t)b * 9 * C_;
    #pragma unroll
    for (int n = 0; n < 4; ++n) {
      float er = S[n * C_ + t];
      float dl = S[(4 + n) * C_ + t];
      float tt = S[8 * C_ + t];
      mid[3 * n][t]     = er;        // er
      mid[3 * n + 1][t] = tt - dl;   // bg = tot - dl
      mid[3 * n + 2][t] = dl - er;   // maskd
    }
  }
  __syncthreads();
  if (t < 12) {
    float s = 0.0f;
    for (int c2 = 0; c2 < 256; ++c2) {
      float sf = gf[c2] * rsqrtf(vf[c2] + EPS_BN);
      float tf = bfp[c2] - muf[c2] * sf;
      s += mid[t][c2] * tf;
    }
    wk[t] = s;
  }
  __syncthreads();
  float mt[12];
  #pragma unroll
  for (int k = 0; k < 12; ++k) mt[k] = mid[k][t];
  const int r0 = x * 64;
  for (int r = 0; r < 64; ++r) {
    const int rr = r0 + r;
    float g = 0.0f;
    #pragma unroll
    for (int k = 0; k < 12; ++k) g += mid[k][rr] * mt[k];
    G[((size_t)b * 256 + rr) * 256 + t] = g;
  }
  if (x == 0) {
    float cst = 0.0f;
    #pragma unroll
    for (int k = 0; k < 12; ++k) cst += mt[k] * wk[k];
    constb[b * 256 + t] = cst;
  }
}

// M2[b] = (G * s_f[col]) @ W_f   (fp32 64x64-tile GEMM)
__global__ __launch_bounds__(256) void k_M2(const float* __restrict__ G,
    const float* __restrict__ Wf, const float* __restrict__ gf,
    const float* __restrict__ vf, float* __restrict__ M2) {
  const int bx = blockIdx.x, by = blockIdx.y, b = blockIdx.z;
  const int t = threadIdx.x, tx = t & 15, ty = t >> 4;
  __shared__ float As[64][17];
  __shared__ float Bs[16][65];
  __shared__ float sf[256];
  sf[t] = gf[t] * rsqrtf(vf[t] + EPS_BN);
  __syncthreads();
  float acc[4][4];
  #pragma unroll
  for (int i = 0; i < 4; ++i)
    #pragma unroll
    for (int j = 0; j < 4; ++j) acc[i][j] = 0.0f;
  const int m0 = bx * 64, n0 = by * 64;
  for (int k0 = 0; k0 < 256; k0 += 16) {
    #pragma unroll
    for (int i = 0; i < 4; ++i) {
      int id = i * 256 + t, mm2 = id >> 4, kk = id & 15;
      As[mm2][kk] = G[((size_t)b * 256 + m0 + mm2) * 256 + k0 + kk] * sf[k0 + kk];
    }
    #pragma unroll
    for (int i = 0; i < 4; ++i) {
      int id = i * 256 + t, kb = id >> 6, nn = id & 63;
      Bs[kb][nn] = Wf[(size_t)(k0 + kb) * 256 + n0 + nn];
    }
    __syncthreads();
    #pragma unroll
    for (int kk = 0; kk < 16; ++kk) {
      float a[4], bb[4];
      #pragma unroll
      for (int i2 = 0; i2 < 4; ++i2) a[i2] = As[ty + 16 * i2][kk];
      #pragma unroll
      for (int j2 = 0; j2 < 4; ++j2) bb[j2] = Bs[kk][tx + 16 * j2];
      #pragma unroll
      for (int i2 = 0; i2 < 4; ++i2)
        #pragma unroll
        for (int j2 = 0; j2 < 4; ++j2) acc[i2][j2] += a[i2] * bb[j2];
    }
    __syncthreads();
  }
  #pragma unroll
  for (int i2 = 0; i2 < 4; ++i2)
    #pragma unroll
    for (int j2 = 0; j2 < 4; ++j2)
      M2[((size_t)b * 256 + m0 + ty + 16 * i2) * 256 + n0 + tx + 16 * j2] = acc[i2][j2];
}

// E[b] = bf16( s_o[o] * (W_o1 + W_o2 @ M2[b]) ); beta[b,o] = s_o*(W_o2@const)+t_o
__global__ __launch_bounds__(256) void k_E(const float* __restrict__ Wo,
    const float* __restrict__ M2, const float* __restrict__ go,
    const float* __restrict__ bo, const float* __restrict__ muo,
    const float* __restrict__ vo, const float* __restrict__ constb,
    bf16_t* __restrict__ E, float* __restrict__ beta) {
  const int bx = blockIdx.x, by = blockIdx.y, b = blockIdx.z;
  const int t = threadIdx.x, tx = t & 15, ty = t >> 4;
  __shared__ float As[64][17];
  __shared__ float Bs[16][65];
  float acc[4][4];
  #pragma unroll
  for (int i = 0; i < 4; ++i)
    #pragma unroll
    for (int j = 0; j < 4; ++j) acc[i][j] = 0.0f;
  const int m0 = bx * 64, n0 = by * 64;
  for (int k0 = 0; k0 < 256; k0 += 16) {
    #pragma unroll
    for (int i = 0; i < 4; ++i) {
      int id = i * 256 + t, mm2 = id >> 4, kk = id & 15;
      As[mm2][kk] = Wo[(size_t)(m0 + mm2) * 512 + 256 + k0 + kk];
    }
    #pragma unroll
    for (int i = 0; i < 4; ++i) {
      int id = i * 256 + t, kb = id >> 6, nn = id & 63;
      Bs[kb][nn] = M2[((size_t)b * 256 + k0 + kb) * 256 + n0 + nn];
    }
    __syncthreads();
    #pragma unroll
    for (int kk = 0; kk < 16; ++kk) {
      float a[4], bb[4];
      #pragma unroll
      for (int i2 = 0; i2 < 4; ++i2) a[i2] = As[ty + 16 * i2][kk];
      #pragma unroll
      for (int j2 = 0; j2 < 4; ++j2) bb[j2] = Bs[kk][tx + 16 * j2];
      #pragma unroll
      for (int i2 = 0; i2 < 4; ++i2)
        #pragma unroll
        for (int j2 = 0; j2 < 4; ++j2) acc[i2][j2] += a[i2] * bb[j2];
    }
    __syncthreads();
  }
  #pragma unroll
  for (int i2 = 0; i2 < 4; ++i2) {
    const int o = m0 + ty + 16 * i2;
    const float so = go[o] * rsqrtf(vo[o] + EPS_BN);
    #pragma unroll
    for (int j2 = 0; j2 < 4; ++j2) {
      const int e = n0 + tx + 16 * j2;
      float val = so * (Wo[(size_t)o * 512 + e] + acc[i2][j2]);
      E[((size_t)b * 256 + o) * 256 + e] = (bf16_t)val;
    }
  }
  if (by == 0 && t < 64) {
    const int o = m0 + t;
    float s = 0.0f;
    for (int c2 = 0; c2 < 256; ++c2)
      s += Wo[(size_t)o * 512 + 256 + c2] * constb[b * 256 + c2];
    const float so = go[o] * rsqrtf(vo[o] + EPS_BN);
    beta[b * 256 + o] = so * s + (bo[o] - muo[o] * so);
  }
}

// out[b,o,p] = sum_c E[b,o,c]*feature[b,c,p] + beta[b,o]   (bf16 MFMA, f32 acc)
// block: 256 thr = 4 waves; tile M=256 (all o), N=64 p; K-steps of 32.
__global__ __launch_bounds__(256) void k_out(const float* __restrict__ f,
    const bf16_t* __restrict__ E, const float* __restrict__ beta,
    float* __restrict__ out) {
  const int pt = blockIdx.x;   // 256 p-tiles
  const int b  = blockIdx.y;
  const int t = threadIdx.x, w = t >> 6, l = t & 63;
  const int p0 = pt * 64;
  __shared__ bf16_t Al[256][40];   // [o][k] padded rows (80B) -> conflict-light
  __shared__ bf16_t Bl[64][40];    // [p][k] (transposed during staging)
  f32x4 acc[4][4];
  #pragma unroll
  for (int i = 0; i < 4; ++i)
    #pragma unroll
    for (int j = 0; j < 4; ++j)
      acc[i][j] = (f32x4){0.0f, 0.0f, 0.0f, 0.0f};
  const bf16_t* Eb = E + (size_t)b * 256 * 256;
  const float* fb = f + (size_t)b * C_ * HW_;
  const int r16 = l & 15, g16 = l >> 4;
  for (int kc = 0; kc < 8; ++kc) {
    __syncthreads();
    // stage A (E, already bf16): 256x32 slab
    #pragma unroll
    for (int i = 0; i < 4; ++i) {
      int id = i * 256 + t;
      int row = id >> 2, cq = id & 3;
      const uint4* gp = (const uint4*)(Eb + (size_t)row * 256 + kc * 32 + cq * 8);
      *(uint4*)&Al[row][cq * 8] = *gp;
    }
    // stage B (feature f32 -> bf16, transposed to [p][k])
    {
      const int cl = t >> 3, q = t & 7;
      const float* sp = fb + (size_t)(kc * 32 + cl) * HW_ + p0 + q * 4;
      const float4 v1 = *(const float4*)sp;
      const float4 v2 = *(const float4*)(sp + 32);
      const float* a1 = (const float*)&v1;
      const float* a2 = (const float*)&v2;
      #pragma unroll
      for (int d = 0; d < 4; ++d) {
        Bl[q * 4 + d][cl]      = (bf16_t)a1[d];
        Bl[q * 4 + 32 + d][cl] = (bf16_t)a2[d];
      }
    }
    __syncthreads();
    bf16x8 af[4], bfr[4];
    #pragma unroll
    for (int mi = 0; mi < 4; ++mi)
      af[mi] = *(const bf16x8*)&Al[w * 64 + mi * 16 + r16][g16 * 8];
    #pragma unroll
    for (int ni = 0; ni < 4; ++ni)
      bfr[ni] = *(const bf16x8*)&Bl[ni * 16 + r16][g16 * 8];
    #pragma unroll
    for (int mi = 0; mi < 4; ++mi)
      #pragma unroll
      for (int ni = 0; ni < 4; ++ni)
        acc[mi][ni] = __builtin_amdgcn_mfma_f32_16x16x32_bf16(af[mi], bfr[ni],
                                                              acc[mi][ni], 0, 0, 0);
  }
  float* ob = out + (size_t)b * C_ * HW_;
  #pragma unroll
  for (int mi = 0; mi < 4; ++mi) {
    #pragma unroll
    for (int j = 0; j < 4; ++j) {
      const int o = w * 64 + mi * 16 + g16 * 4 + j;
      const float bet = beta[b * 256 + o];
      #pragma unroll
      for (int ni = 0; ni < 4; ++ni)
        ob[(size_t)o * HW_ + p0 + ni * 16 + r16] = acc[mi][ni][j] + bet;
    }
  }
}

extern "C" void kernel_launch(void* const* d_in, const int* in_sizes, int n_in,
                              void* d_out, int out_size, void* d_ws, size_t ws_size,
                              hipStream_t stream) {
  (void)in_sizes; (void)n_in; (void)out_size; (void)ws_size;
  const float* feature = (const float*)d_in[0];
  const float* m_in = (const float*)d_in[1];
  const float* W_f  = (const float*)d_in[2];
  const float* g_f  = (const float*)d_in[3];
  const float* b_f  = (const float*)d_in[4];
  const float* mu_f = (const float*)d_in[5];
  const float* v_f  = (const float*)d_in[6];
  const float* W_o  = (const float*)d_in[7];
  const float* g_o  = (const float*)d_in[8];
  const float* b_o  = (const float*)d_in[9];
  const float* mu_o = (const float*)d_in[10];
  const float* v_o  = (const float*)d_in[11];
  float* out = (float*)d_out;
  char* ws = (char*)d_ws;
  // ws layout (bytes)
  uint32_t* maskw  = (uint32_t*)(ws + 0);        // 131072
  uint8_t*  maskb  = (uint8_t*)(ws + 0);
  float*    Smid   = (float*)(ws + 131072);      // 73728
  float*    G      = (float*)(ws + 204800);      // 2097152
  float*    constb = (float*)(ws + 2301952);     // 8192
  float*    M2     = (float*)(ws + 2310144);     // 2097152
  bf16_t*   E      = (bf16_t*)(ws + 4407296);    // 1048576
  float*    beta   = (float*)(ws + 5455872);     // 8192
  // total 5464064 bytes

  hipMemsetAsync(ws, 0, 204800, stream);  // maskw + Smid
  k_masks<<<dim3(4, 8), 256, 0, stream>>>(m_in, maskw);
  k_midsum<<<dim3(16, 4, 8), 256, 0, stream>>>(feature, maskb, Smid);
  k_G<<<dim3(4, 8), 256, 0, stream>>>(Smid, g_f, b_f, mu_f, v_f, G, constb);
  k_M2<<<dim3(4, 4, 8), 256, 0, stream>>>(G, W_f, g_f, v_f, M2);
  k_E<<<dim3(4, 4, 8), 256, 0, stream>>>(W_o, M2, g_o, b_o, mu_o, v_o, constb, E, beta);
  k_out<<<dim3(256, 8), 256, 0, stream>>>(feature, E, beta, out);
}